// Round 6
// baseline (45.526 us; speedup 1.0000x reference)
//
#include <hip/hip_runtime.h>
#include <math.h>

// Problem geometry (fixed by the reference):
//   pred, gt : [16, 32, 256, 256] float32   (128 MiB each; 256 MiB total = L3 size)
//   out[b] = (1/32) * sum_{c,h,w} bce(pred, 0.9*gt + 0.1/256)
// Identity: max(x,0) - x*t + log1p(exp(-|x|)) = log(1+exp(x)) - x*t   (exact)
// Factored: sum bce = ln2 * sum(log2(1+e^x)) - 0.9*sum(x*g) - (0.1/256)*sum(x)
//
// L3 strategy: working set == L3 capacity exactly -> default replacement gives
// ~49% hit (FETCH_SIZE 131 MB at 44.6us, both HBM and L3 under-utilized).
// Load gt with nontemporal hint (evict-first, no L3 displacement of pred) so
// pred (128 MiB) becomes fully L3-resident; gt streams from HBM at full rate.

#define B_DIM 16
#define ELEMS_PER_BATCH (32 * 256 * 256)   // 2,097,152
#define BPB 128                            // blocks per batch
#define TPB 256                            // threads per block

typedef float v4f __attribute__((ext_vector_type(4)));

__global__ __launch_bounds__(TPB) void bce_partial_kernel(
        const float* __restrict__ pred,
        const float* __restrict__ gt,
        float* __restrict__ partials) {
    const int b   = blockIdx.x / BPB;
    const int blk = blockIdx.x % BPB;
    const long long base = (long long)b * ELEMS_PER_BATCH;

    const v4f* __restrict__ p4 = (const v4f*)(pred + base);
    const v4f* __restrict__ g4 = (const v4f*)(gt + base);

    const int per_block = (ELEMS_PER_BATCH / 4) / BPB;  // 4,096 float4
    const int start     = blk * per_block;

    // Each thread: 2 float4 per array per iteration (64B in flight/iter),
    // 8 iterations total. Dual accumulator sets -> independent add chains.
    float sp0 = 0.f, sp1 = 0.f;   // sum log2(1+e^x)
    float xg0 = 0.f, xg1 = 0.f;   // sum x*g
    float xs0 = 0.f, xs1 = 0.f;   // sum x

    #pragma unroll
    for (int it = 0; it < 8; ++it) {
        const int i0 = start + it * (2 * TPB) + threadIdx.x;
        const int i1 = i0 + TPB;
        v4f xa = p4[i0];                                 // pred: cached (L3-resident)
        v4f xb = p4[i1];
        v4f ga = __builtin_nontemporal_load(&g4[i0]);    // gt: nt, stream from HBM
        v4f gb = __builtin_nontemporal_load(&g4[i1]);

        sp0 += __log2f(1.0f + __expf(xa.x));
        sp1 += __log2f(1.0f + __expf(xa.y));
        sp0 += __log2f(1.0f + __expf(xa.z));
        sp1 += __log2f(1.0f + __expf(xa.w));
        sp0 += __log2f(1.0f + __expf(xb.x));
        sp1 += __log2f(1.0f + __expf(xb.y));
        sp0 += __log2f(1.0f + __expf(xb.z));
        sp1 += __log2f(1.0f + __expf(xb.w));

        xg0 = __builtin_fmaf(xa.x, ga.x, xg0);
        xg1 = __builtin_fmaf(xa.y, ga.y, xg1);
        xg0 = __builtin_fmaf(xa.z, ga.z, xg0);
        xg1 = __builtin_fmaf(xa.w, ga.w, xg1);
        xg0 = __builtin_fmaf(xb.x, gb.x, xg0);
        xg1 = __builtin_fmaf(xb.y, gb.y, xg1);
        xg0 = __builtin_fmaf(xb.z, gb.z, xg0);
        xg1 = __builtin_fmaf(xb.w, gb.w, xg1);

        xs0 += (xa.x + xa.y) + (xb.x + xb.y);
        xs1 += (xa.z + xa.w) + (xb.z + xb.w);
    }

    float acc = 0.6931471805599453f * (sp0 + sp1)
              - 0.9f               * (xg0 + xg1)
              - (0.1f / 256.0f)    * (xs0 + xs1);

    // wave-64 shuffle reduction
    #pragma unroll
    for (int off = 32; off > 0; off >>= 1)
        acc += __shfl_down(acc, off, 64);

    __shared__ float smem[TPB / 64];
    if ((threadIdx.x & 63) == 0) smem[threadIdx.x >> 6] = acc;
    __syncthreads();

    if (threadIdx.x == 0) {
        float s = smem[0] + smem[1] + smem[2] + smem[3];
        partials[b * BPB + blk] = s;
    }
}

__global__ __launch_bounds__(64) void bce_finalize_kernel(
        const float* __restrict__ partials,
        float* __restrict__ out) {
    const int b = blockIdx.x;
    float acc = 0.0f;
    for (int i = threadIdx.x; i < BPB; i += 64)
        acc += partials[b * BPB + i];
    #pragma unroll
    for (int off = 32; off > 0; off >>= 1)
        acc += __shfl_down(acc, off, 64);
    if (threadIdx.x == 0)
        out[b] = acc * (1.0f / 32.0f);   // mean over channels
}

extern "C" void kernel_launch(void* const* d_in, const int* in_sizes, int n_in,
                              void* d_out, int out_size, void* d_ws, size_t ws_size,
                              hipStream_t stream) {
    const float* pred = (const float*)d_in[0];
    const float* gt   = (const float*)d_in[1];
    float* out        = (float*)d_out;
    float* partials   = (float*)d_ws;    // needs 16*128*4 = 8 KB

    bce_partial_kernel<<<B_DIM * BPB, TPB, 0, stream>>>(pred, gt, partials);
    bce_finalize_kernel<<<B_DIM, 64, 0, stream>>>(partials, out);
}